// Round 3
// baseline (114.056 us; speedup 1.0000x reference)
//
#include <hip/hip_runtime.h>

// Problem constants
constexpr int W   = 240;
constexpr int H   = 128;
constexpr int D   = 48;   // disparity bins
constexpr int G   = 40;   // groups
constexpr int CPG = 8;    // channels per group (320/40)
constexpr int CC  = 12;   // concat channels
constexpr int HW  = H * W;
constexpr int PAD = 48;        // left zero-pad so tgt[w-d] (w<d) reads zeros
constexpr int TROW = PAD + W;  // 288 floats per padded row

constexpr int NGWC = G * H;       // 5120 gwc blocks
constexpr int NCAT = 2 * CC * H;  // 3072 concat blocks (c2 0..23 x h)
// Interleave 5 gwc : 3 cat per group of 8 consecutive blockIdx (5120/3072 = 5/3)
constexpr int NGRID = NGWC + NCAT;  // 8192

// Stores are PLAIN cached float4 (dwordx4). Rationale: nt/streaming stores
// evict dirty lines from L2 ~immediately -> HBM controller sees scattered
// 64-960B writes from ~6k waves (poor DRAM page locality, measured 4.4 TB/s
// drain). Plain stores let L2 (4MB/XCD) batch dirty lines and drain in
// larger runs -- the rocclr fill sustains 7.0 TB/s this way. Loads stay
// PLAIN (cached): nt loads measured +9.3us (round 1; inputs are L3-warm).
__device__ __forceinline__ void st4(float* p, float4 v) {
  *(float4*)p = v;
}

// ---------------------------------------------------------------------------
// Fused kernel.
// Type A (gwc): one block per (g, h). LDS ref[8][240] + tgt[8][288 padded].
//   lane = w4 (60 active), wave dq -> 12 consecutive d via one aligned
//   16-float register window per channel + static slices. mean/8 epilogue.
// Type B (cat): one block per (c2, h). LDS one padded row. Same lane/d
//   mapping; ref half = mask-select, tgt half = window slices. Pure copy.
// ---------------------------------------------------------------------------
__global__ __launch_bounds__(256) void fused_kernel(const float* __restrict__ ref,
                                                    const float* __restrict__ tgt,
                                                    const float* __restrict__ refc,
                                                    const float* __restrict__ tgtc,
                                                    float* __restrict__ out) {
  __shared__ float sref[CPG][W];
  __shared__ float stgt[CPG][TROW];

  const int bid = blockIdx.x;
  const int grp = bid >> 3;
  const int rr  = bid & 7;
  const int tid = threadIdx.x;

  const int lane = tid & 63;
  const int dq   = tid >> 6;   // 0..3 -> d block of 12
  const int w4   = lane;       // active if < 60
  const int d0   = dq * 12;

  if (rr < 5) {
    // ---------------- Type A: groupwise correlation ----------------
    const int aid = grp * 5 + rr;      // 0..5119
    const int g   = aid >> 7;
    const int h   = aid & (H - 1);

    for (int p = tid; p < CPG * (PAD / 4); p += 256) {
      int c = p / (PAD / 4);
      int i = p - c * (PAD / 4);
      *(float4*)&stgt[c][i * 4] = make_float4(0.f, 0.f, 0.f, 0.f);
    }
    const size_t rowbase = (size_t)(g * CPG) * HW + (size_t)h * W;
    for (int q = tid; q < CPG * (W / 4); q += 256) {
      int c  = q / (W / 4);
      int x4 = q - c * (W / 4);
      float4 rv = *(const float4*)&ref[rowbase + (size_t)c * HW + x4 * 4];
      float4 tv = *(const float4*)&tgt[rowbase + (size_t)c * HW + x4 * 4];
      *(float4*)&sref[c][x4 * 4]       = rv;
      *(float4*)&stgt[c][PAD + x4 * 4] = tv;
    }
    __syncthreads();
    if (w4 >= W / 4) return;

    float4 acc[12];
#pragma unroll
    for (int j = 0; j < 12; ++j) acc[j] = make_float4(0.f, 0.f, 0.f, 0.f);

    const int base = 4 * w4 - d0 - 12;   // aligned (d0 % 4 == 0)
#pragma unroll
    for (int c = 0; c < CPG; ++c) {
      float4 r = *(const float4*)&sref[c][4 * w4];
      const float4* tp = (const float4*)&stgt[c][PAD + base];
      float tt[16];
      *(float4*)&tt[0]  = tp[0];
      *(float4*)&tt[4]  = tp[1];
      *(float4*)&tt[8]  = tp[2];
      *(float4*)&tt[12] = tp[3];
#pragma unroll
      for (int j = 0; j < 12; ++j) {   // d = d0 + j; window = tt[12-j .. 15-j]
        acc[j].x += r.x * tt[12 - j];
        acc[j].y += r.y * tt[13 - j];
        acc[j].z += r.z * tt[14 - j];
        acc[j].w += r.w * tt[15 - j];
      }
    }

    float* op = out + ((size_t)(g * D + d0) * H + h) * W + 4 * w4;
#pragma unroll
    for (int j = 0; j < 12; ++j) {
      st4(op, make_float4(acc[j].x * 0.125f, acc[j].y * 0.125f,
                          acc[j].z * 0.125f, acc[j].w * 0.125f));
      op += HW;
    }
  } else {
    // ---------------- Type B: concat volume ----------------
    const int cid = grp * 3 + (rr - 5);  // 0..3071
    const int c2  = cid >> 7;            // 0..23
    const int h   = cid & (H - 1);
    float* srow = &stgt[0][0];           // TROW floats

    if (tid < PAD / 4)
      *(float4*)&srow[tid * 4] = make_float4(0.f, 0.f, 0.f, 0.f);
    const bool is_ref = (c2 < CC);
    const float* src = is_ref ? (refc + (size_t)c2 * HW + (size_t)h * W)
                              : (tgtc + (size_t)(c2 - CC) * HW + (size_t)h * W);
    if (tid < W / 4)
      *(float4*)&srow[PAD + tid * 4] = *(const float4*)&src[tid * 4];
    __syncthreads();
    if (w4 >= W / 4) return;

    float* op = out + ((size_t)((G + c2) * D + d0) * H + h) * W + 4 * w4;
    if (is_ref) {
      const float4 rv = *(const float4*)&srow[PAD + 4 * w4];
      const int w0 = 4 * w4;
#pragma unroll
      for (int j = 0; j < 12; ++j) {
        const int d = d0 + j;
        float4 v;
        v.x = (w0 + 0 >= d) ? rv.x : 0.f;
        v.y = (w0 + 1 >= d) ? rv.y : 0.f;
        v.z = (w0 + 2 >= d) ? rv.z : 0.f;
        v.w = (w0 + 3 >= d) ? rv.w : 0.f;
        st4(op, v);
        op += HW;
      }
    } else {
      const int base = 4 * w4 - d0 - 12;
      const float4* tp = (const float4*)&srow[PAD + base];
      float tt[16];
      *(float4*)&tt[0]  = tp[0];
      *(float4*)&tt[4]  = tp[1];
      *(float4*)&tt[8]  = tp[2];
      *(float4*)&tt[12] = tp[3];
#pragma unroll
      for (int j = 0; j < 12; ++j) {
        st4(op, make_float4(tt[12 - j], tt[13 - j], tt[14 - j], tt[15 - j]));
        op += HW;
      }
    }
  }
}

extern "C" void kernel_launch(void* const* d_in, const int* in_sizes, int n_in,
                              void* d_out, int out_size, void* d_ws, size_t ws_size,
                              hipStream_t stream) {
  const float* ref_gwc    = (const float*)d_in[0];
  const float* tgt_gwc    = (const float*)d_in[1];
  const float* ref_concat = (const float*)d_in[2];
  const float* tgt_concat = (const float*)d_in[3];
  float* out = (float*)d_out;

  fused_kernel<<<NGRID, 256, 0, stream>>>(ref_gwc, tgt_gwc, ref_concat,
                                          tgt_concat, out);
}

// Round 4
// 90.342 us; speedup vs baseline: 1.2625x; 1.2625x over previous
//
#include <hip/hip_runtime.h>

// Problem constants
constexpr int W   = 240;
constexpr int H   = 128;
constexpr int D   = 48;   // disparity bins
constexpr int G   = 40;   // groups
constexpr int CPG = 8;    // channels per group (320/40)
constexpr int CC  = 12;   // concat channels
constexpr int HW  = H * W;
constexpr int PAD = 48;        // left zero-pad so tgt[w-d] (w<d) reads zeros
constexpr int TROW = PAD + W;  // 288 floats per padded row

// h-chunk restructure for DRAM write locality: each block covers 8 adjacent
// h rows and loops over them, so ONE wave writes rows h0..h0+7 of each of
// its 12 d-planes sequentially in time -> 7.7KB in-order runs per plane
// (vs 960B chunks from 128 scattered blocks in the flat decomposition).
// Stores stay scalar-nt (85.8us-verified flavor); loads stay cached
// (nt loads +9.3us, round 1); double-buffered LDS with async-split staging
// (issue loads before compute, LDS-write after) hides row-load latency.
constexpr int HC   = 8;             // h rows per block
constexpr int NHC  = H / HC;        // 16 chunks
constexpr int NGWC = G * NHC;       // 640 gwc blocks
constexpr int NCAT = 2 * CC * NHC;  // 384 concat blocks
// Interleave 5 gwc : 3 cat per group of 8 consecutive blockIdx (640/384 = 5/3)
constexpr int NGRID = NGWC + NCAT;  // 1024

__device__ __forceinline__ void nt_store4(float* p, float4 v) {
  __builtin_nontemporal_store(v.x, p + 0);
  __builtin_nontemporal_store(v.y, p + 1);
  __builtin_nontemporal_store(v.z, p + 2);
  __builtin_nontemporal_store(v.w, p + 3);
}

// ---------------------------------------------------------------------------
// Type A (gwc): one block per (g, h-chunk). LDS dbuf ref[2][8][240] +
//   tgt[2][8][288 padded]. lane = w4 (60 active), wave dq -> 12 consecutive
//   d via one aligned 16-float register window per channel. Loop h0..h0+7.
// Type B (cat): one block per (c2, h-chunk). LDS dbuf one padded row.
//   Same lane/d mapping; ref half = mask-select, tgt half = window slices.
// ---------------------------------------------------------------------------
__global__ __launch_bounds__(256) void fused_kernel(const float* __restrict__ ref,
                                                    const float* __restrict__ tgt,
                                                    const float* __restrict__ refc,
                                                    const float* __restrict__ tgtc,
                                                    float* __restrict__ out) {
  __shared__ float sref[2][CPG][W];     // 15360 B
  __shared__ float stgt[2][CPG][TROW];  // 18432 B

  const int bid = blockIdx.x;
  const int grp = bid >> 3;
  const int rr  = bid & 7;
  const int tid = threadIdx.x;

  const int lane = tid & 63;
  const int dq   = tid >> 6;   // 0..3 -> d block of 12
  const int w4   = lane;       // active if < 60
  const int d0   = dq * 12;

  if (rr < 5) {
    // ---------------- Type A: groupwise correlation ----------------
    const int aid = grp * 5 + rr;      // 0..639
    const int g   = aid >> 4;          // 0..39
    const int h0  = (aid & 15) * HC;   // 0,8,..,120

    // zero left pads of BOTH buffers once (stage never touches [0..PAD))
    for (int p = tid; p < 2 * CPG * (PAD / 4); p += 256) {  // 192 slots
      int b = p / (CPG * (PAD / 4));
      int r = p - b * (CPG * (PAD / 4));
      int c = r / (PAD / 4);
      int i = r - c * (PAD / 4);
      *(float4*)&stgt[b][c][i * 4] = make_float4(0.f, 0.f, 0.f, 0.f);
    }

    // per-thread staging slots: q0 = tid, q1 = tid + 256 (480 slots total)
    const int  q0c = tid / (W / 4), q0x = tid - q0c * (W / 4);
    const int  q1  = tid + 256;
    const bool q1v = q1 < CPG * (W / 4);
    const int  q1c = q1 / (W / 4), q1x = q1 - q1c * (W / 4);

    const size_t gbase = (size_t)(g * CPG) * HW;
    const size_t a0 = gbase + (size_t)q0c * HW + q0x * 4;
    const size_t a1 = gbase + (size_t)q1c * HW + q1x * 4;

    // prologue: stage row h0 into buf 0
    {
      const size_t hoff = (size_t)h0 * W;
      float4 rv0 = *(const float4*)&ref[a0 + hoff];
      float4 tv0 = *(const float4*)&tgt[a0 + hoff];
      *(float4*)&sref[0][q0c][q0x * 4]       = rv0;
      *(float4*)&stgt[0][q0c][PAD + q0x * 4] = tv0;
      if (q1v) {
        float4 rv1 = *(const float4*)&ref[a1 + hoff];
        float4 tv1 = *(const float4*)&tgt[a1 + hoff];
        *(float4*)&sref[0][q1c][q1x * 4]       = rv1;
        *(float4*)&stgt[0][q1c][PAD + q1x * 4] = tv1;
      }
    }
    __syncthreads();

    for (int hh = 0; hh < HC; ++hh) {
      const int  b  = hh & 1;
      const bool pf = (hh + 1 < HC);
      float4 rv0, tv0, rv1, tv1;
      if (pf) {  // issue next-row loads BEFORE compute (latency hides under FMAs)
        const size_t hoff = (size_t)(h0 + hh + 1) * W;
        rv0 = *(const float4*)&ref[a0 + hoff];
        tv0 = *(const float4*)&tgt[a0 + hoff];
        if (q1v) {
          rv1 = *(const float4*)&ref[a1 + hoff];
          tv1 = *(const float4*)&tgt[a1 + hoff];
        }
      }

      if (w4 < W / 4) {
        float4 acc[12];
#pragma unroll
        for (int j = 0; j < 12; ++j) acc[j] = make_float4(0.f, 0.f, 0.f, 0.f);

        const int base = 4 * w4 - d0 - 12;  // aligned (d0 % 4 == 0)
#pragma unroll
        for (int c = 0; c < CPG; ++c) {
          float4 r = *(const float4*)&sref[b][c][4 * w4];
          const float4* tp = (const float4*)&stgt[b][c][PAD + base];
          float tt[16];
          *(float4*)&tt[0]  = tp[0];
          *(float4*)&tt[4]  = tp[1];
          *(float4*)&tt[8]  = tp[2];
          *(float4*)&tt[12] = tp[3];
#pragma unroll
          for (int j = 0; j < 12; ++j) {  // d = d0 + j; window = tt[12-j..15-j]
            acc[j].x += r.x * tt[12 - j];
            acc[j].y += r.y * tt[13 - j];
            acc[j].z += r.z * tt[14 - j];
            acc[j].w += r.w * tt[15 - j];
          }
        }

        float* op = out + ((size_t)(g * D + d0) * H + (h0 + hh)) * W + 4 * w4;
#pragma unroll
        for (int j = 0; j < 12; ++j) {
          nt_store4(op, make_float4(acc[j].x * 0.125f, acc[j].y * 0.125f,
                                    acc[j].z * 0.125f, acc[j].w * 0.125f));
          op += HW;
        }
      }

      if (pf) {  // LDS-write the prefetched row AFTER compute
        *(float4*)&sref[b ^ 1][q0c][q0x * 4]       = rv0;
        *(float4*)&stgt[b ^ 1][q0c][PAD + q0x * 4] = tv0;
        if (q1v) {
          *(float4*)&sref[b ^ 1][q1c][q1x * 4]       = rv1;
          *(float4*)&stgt[b ^ 1][q1c][PAD + q1x * 4] = tv1;
        }
      }
      __syncthreads();
    }
  } else {
    // ---------------- Type B: concat volume ----------------
    const int cid = grp * 3 + (rr - 5);  // 0..383
    const int c2  = cid >> 4;            // 0..23
    const int h0  = (cid & 15) * HC;
    const bool is_ref = (c2 < CC);
    const float* src = is_ref ? (refc + (size_t)c2 * HW)
                              : (tgtc + (size_t)(c2 - CC) * HW);

    // two padded row buffers live at stgt[0..1][0][*]; zero pads once
    if (tid < 2 * (PAD / 4)) {  // 24
      int b = tid / (PAD / 4);
      int i = tid - b * (PAD / 4);
      *(float4*)&stgt[b][0][i * 4] = make_float4(0.f, 0.f, 0.f, 0.f);
    }
    if (tid < W / 4)
      *(float4*)&stgt[0][0][PAD + tid * 4] =
          *(const float4*)&src[(size_t)h0 * W + tid * 4];
    __syncthreads();

    for (int hh = 0; hh < HC; ++hh) {
      const int  b  = hh & 1;
      const bool pf = (hh + 1 < HC);
      float4 nv;
      if (pf && tid < W / 4)
        nv = *(const float4*)&src[(size_t)(h0 + hh + 1) * W + tid * 4];

      if (w4 < W / 4) {
        const float* srow = &stgt[b][0][0];
        float* op =
            out + ((size_t)((G + c2) * D + d0) * H + (h0 + hh)) * W + 4 * w4;
        if (is_ref) {
          const float4 rv = *(const float4*)&srow[PAD + 4 * w4];
          const int w0 = 4 * w4;
#pragma unroll
          for (int j = 0; j < 12; ++j) {
            const int d = d0 + j;
            float4 v;
            v.x = (w0 + 0 >= d) ? rv.x : 0.f;
            v.y = (w0 + 1 >= d) ? rv.y : 0.f;
            v.z = (w0 + 2 >= d) ? rv.z : 0.f;
            v.w = (w0 + 3 >= d) ? rv.w : 0.f;
            nt_store4(op, v);
            op += HW;
          }
        } else {
          const int base = 4 * w4 - d0 - 12;
          const float4* tp = (const float4*)&srow[PAD + base];
          float tt[16];
          *(float4*)&tt[0]  = tp[0];
          *(float4*)&tt[4]  = tp[1];
          *(float4*)&tt[8]  = tp[2];
          *(float4*)&tt[12] = tp[3];
#pragma unroll
          for (int j = 0; j < 12; ++j) {
            nt_store4(op,
                      make_float4(tt[12 - j], tt[13 - j], tt[14 - j], tt[15 - j]));
            op += HW;
          }
        }
      }

      if (pf && tid < W / 4)
        *(float4*)&stgt[b ^ 1][0][PAD + tid * 4] = nv;
      __syncthreads();
    }
  }
}

extern "C" void kernel_launch(void* const* d_in, const int* in_sizes, int n_in,
                              void* d_out, int out_size, void* d_ws, size_t ws_size,
                              hipStream_t stream) {
  const float* ref_gwc    = (const float*)d_in[0];
  const float* tgt_gwc    = (const float*)d_in[1];
  const float* ref_concat = (const float*)d_in[2];
  const float* tgt_concat = (const float*)d_in[3];
  float* out = (float*)d_out;

  fused_kernel<<<NGRID, 256, 0, stream>>>(ref_gwc, tgt_gwc, ref_concat,
                                          tgt_concat, out);
}

// Round 5
// 88.127 us; speedup vs baseline: 1.2942x; 1.0251x over previous
//
#include <hip/hip_runtime.h>

// Problem constants
constexpr int W   = 240;
constexpr int H   = 128;
constexpr int D   = 48;   // disparity bins
constexpr int G   = 40;   // groups
constexpr int CPG = 8;    // channels per group (320/40)
constexpr int CC  = 12;   // concat channels
constexpr int HW  = H * W;

constexpr int NGWC = G * H;       // 5120 gwc blocks
constexpr int NCAT = 2 * CC * H;  // 3072 concat blocks (c2 0..23 x h)
// Interleave 5 gwc : 3 cat per group of 8 consecutive blockIdx (5120/3072 = 5/3)
constexpr int NGRID = NGWC + NCAT;  // 8192

// Store flavor: scalar nontemporal quads (85.8us-verified round 0).
// Loads: plain cached (nt loads regressed, round 1). Tested+rejected:
// cached stores (+28us, r3), f4-nt-store+nt-load bundle (+9.3, r1),
// h-pair cross-wave write adjacency (+3.3, r2), h-chunk sequential write
// order (+4.5, r4). This round: NO LDS, NO barriers -- each lane sources
// its 16-float tgt window directly from global (4 aligned float4 chunks,
// each chunk fully in-bounds or fully w<0 -> zero). Removes the
// stage->syncthreads->burst-48-stores convoy so store issue is smooth and
// staging instructions vanish; L1/L2 absorb the overlapping-window reads.
__device__ __forceinline__ void nt_store4(float* p, float4 v) {
  __builtin_nontemporal_store(v.x, p + 0);
  __builtin_nontemporal_store(v.y, p + 1);
  __builtin_nontemporal_store(v.z, p + 2);
  __builtin_nontemporal_store(v.w, p + 3);
}

// ---------------------------------------------------------------------------
// Type A (gwc): one block per (g, h). lane = w4 (60 active), wave dq -> 12
//   consecutive d. Per channel: r = ref float4, tt = 16-float tgt window
//   loaded as 4 predicated float4 chunks straight from global. mean/8.
// Type B (cat): one block per (c2, h). ref half = mask-select of own float4;
//   tgt half = same direct-window trick. Pure register dataflow.
// ---------------------------------------------------------------------------
__global__ __launch_bounds__(256, 4) void fused_kernel(
    const float* __restrict__ ref, const float* __restrict__ tgt,
    const float* __restrict__ refc, const float* __restrict__ tgtc,
    float* __restrict__ out) {
  const int bid = blockIdx.x;
  const int grp = bid >> 3;
  const int rr  = bid & 7;
  const int tid = threadIdx.x;

  const int lane = tid & 63;
  const int dq   = tid >> 6;   // 0..3 -> d block of 12
  const int w4   = lane;       // active if < 60
  const int d0   = dq * 12;

  if (w4 >= W / 4) return;     // no barriers anywhere -> safe early exit

  const int base = 4 * w4 - d0 - 12;  // window start; base % 4 == 0

  if (rr < 5) {
    // ---------------- Type A: groupwise correlation ----------------
    const int aid = grp * 5 + rr;      // 0..5119
    const int g   = aid >> 7;
    const int h   = aid & (H - 1);
    const size_t rowbase = (size_t)(g * CPG) * HW + (size_t)h * W;

    float4 acc[12];
#pragma unroll
    for (int j = 0; j < 12; ++j) acc[j] = make_float4(0.f, 0.f, 0.f, 0.f);

#pragma unroll 2
    for (int c = 0; c < CPG; ++c) {
      const float* rp = ref + rowbase + (size_t)c * HW;
      const float* tp = tgt + rowbase + (size_t)c * HW;
      float4 r = *(const float4*)(rp + 4 * w4);
      float tt[16];
#pragma unroll
      for (int k = 0; k < 4; ++k) {
        const int s = base + 4 * k;  // chunk fully in-bounds or fully < 0
        float4 v = make_float4(0.f, 0.f, 0.f, 0.f);
        if (s >= 0) v = *(const float4*)(tp + s);
        *(float4*)&tt[4 * k] = v;
      }
#pragma unroll
      for (int j = 0; j < 12; ++j) {  // d = d0 + j; window = tt[12-j .. 15-j]
        acc[j].x += r.x * tt[12 - j];
        acc[j].y += r.y * tt[13 - j];
        acc[j].z += r.z * tt[14 - j];
        acc[j].w += r.w * tt[15 - j];
      }
    }

    float* op = out + ((size_t)(g * D + d0) * H + h) * W + 4 * w4;
#pragma unroll
    for (int j = 0; j < 12; ++j) {
      nt_store4(op, make_float4(acc[j].x * 0.125f, acc[j].y * 0.125f,
                                acc[j].z * 0.125f, acc[j].w * 0.125f));
      op += HW;
    }
  } else {
    // ---------------- Type B: concat volume ----------------
    const int cid = grp * 3 + (rr - 5);  // 0..3071
    const int c2  = cid >> 7;            // 0..23
    const int h   = cid & (H - 1);
    const bool is_ref = (c2 < CC);

    float* op = out + ((size_t)((G + c2) * D + d0) * H + h) * W + 4 * w4;
    if (is_ref) {
      const float* sp = refc + (size_t)c2 * HW + (size_t)h * W;
      const float4 rv = *(const float4*)(sp + 4 * w4);
      const int w0 = 4 * w4;
#pragma unroll
      for (int j = 0; j < 12; ++j) {
        const int d = d0 + j;
        float4 v;
        v.x = (w0 + 0 >= d) ? rv.x : 0.f;
        v.y = (w0 + 1 >= d) ? rv.y : 0.f;
        v.z = (w0 + 2 >= d) ? rv.z : 0.f;
        v.w = (w0 + 3 >= d) ? rv.w : 0.f;
        nt_store4(op, v);
        op += HW;
      }
    } else {
      const float* sp = tgtc + (size_t)(c2 - CC) * HW + (size_t)h * W;
      float tt[16];
#pragma unroll
      for (int k = 0; k < 4; ++k) {
        const int s = base + 4 * k;
        float4 v = make_float4(0.f, 0.f, 0.f, 0.f);
        if (s >= 0) v = *(const float4*)(sp + s);
        *(float4*)&tt[4 * k] = v;
      }
#pragma unroll
      for (int j = 0; j < 12; ++j) {
        nt_store4(op, make_float4(tt[12 - j], tt[13 - j], tt[14 - j], tt[15 - j]));
        op += HW;
      }
    }
  }
}

extern "C" void kernel_launch(void* const* d_in, const int* in_sizes, int n_in,
                              void* d_out, int out_size, void* d_ws, size_t ws_size,
                              hipStream_t stream) {
  const float* ref_gwc    = (const float*)d_in[0];
  const float* tgt_gwc    = (const float*)d_in[1];
  const float* ref_concat = (const float*)d_in[2];
  const float* tgt_concat = (const float*)d_in[3];
  float* out = (float*)d_out;

  fused_kernel<<<NGRID, 256, 0, stream>>>(ref_gwc, tgt_gwc, ref_concat,
                                          tgt_concat, out);
}